// Round 1
// baseline (217.134 us; speedup 1.0000x reference)
//
#include <hip/hip_runtime.h>
#include <hip/hip_bf16.h>

#define BB 4
#define CC 256
#define CHH 128
#define NN 4096
#define KSHIFT 12.0f

typedef __attribute__((ext_vector_type(8))) short bf16x8;
typedef __attribute__((ext_vector_type(4))) float f32x4;

__device__ __forceinline__ float to_f(float v) { return v; }
__device__ __forceinline__ float to_f(__hip_bfloat16 v) { return __bfloat162float(v); }
__device__ __forceinline__ void st_f(float* p, float v) { *p = v; }
__device__ __forceinline__ void st_f(__hip_bfloat16* p, float v) { *p = __float2bfloat16(v); }
__device__ __forceinline__ unsigned short f2bf(float f) {
    __hip_bfloat16 h = __float2bfloat16(f);
    unsigned short u;
    __builtin_memcpy(&u, &h, 2);
    return u;
}
__device__ __forceinline__ bf16x8 ldb8(const unsigned short* p) { return *(const bf16x8*)p; }

// async global->LDS, 16 B per lane. LDS dest = wave-uniform base + lane*16.
__device__ __forceinline__ void gload_lds16(const unsigned short* g, unsigned short* l) {
    __builtin_amdgcn_global_load_lds(
        (const __attribute__((address_space(1))) unsigned int*)g,
        (__attribute__((address_space(3))) unsigned int*)l, 16, 0, 0);
}

// ---------------------------------------------------------------------------
// Kernel 0: wire-dtype detection (proven rounds 3-10 — keep).
// ---------------------------------------------------------------------------
__global__ void detect_kernel(const void* __restrict__ tb, int* __restrict__ flag) {
    if (threadIdx.x == 0) {
        const __hip_bfloat16* p = (const __hip_bfloat16*)tb;
        int big = 0, zeros = 0;
        for (int i = 0; i < 128; ++i) {
            float v = __bfloat162float(p[i]);
            if (!(fabsf(v) <= 0.5f)) big = 1;
            if ((i & 1) == 0 && v == 0.0f) zeros++;
        }
        *flag = (big || zeros >= 32) ? 1 : 0;
    }
}

// ---------------------------------------------------------------------------
// Kernel 1: convert all weights/biases once (proven round 6).
// ---------------------------------------------------------------------------
template <typename T>
__device__ __forceinline__ void prep_body(const T* tw, const T* fw, const T* gw, const T* ow,
                                          const T* tb2, const T* fb, const T* gb, const T* ob,
                                          unsigned short* Wb, unsigned short* OWb,
                                          float* Bf, float* OBf) {
    int idx = blockIdx.x * 256 + threadIdx.x;
    if (idx < 98304) {
        int cv = idx >> 15, rem = idx & 32767;
        const T* src = cv == 0 ? tw : (cv == 1 ? fw : gw);
        Wb[idx] = f2bf(to_f(src[rem]));
    } else if (idx < 131072) {
        OWb[idx - 98304] = f2bf(to_f(ow[idx - 98304]));
    } else if (idx < 131456) {
        int r = idx - 131072;
        int cv = r >> 7, j = r & 127;
        const T* src = cv == 0 ? tb2 : (cv == 1 ? fb : gb);
        Bf[r] = to_f(src[j]);
    } else if (idx < 131712) {
        OBf[idx - 131456] = to_f(ob[idx - 131456]);
    }
}

__global__ void prep_kernel(const void* tw, const void* fw, const void* gw, const void* ow,
                            const void* tb2, const void* fb, const void* gb, const void* ob,
                            const int* __restrict__ flag,
                            unsigned short* Wb, unsigned short* OWb, float* Bf, float* OBf) {
    if (*flag)
        prep_body<float>((const float*)tw, (const float*)fw, (const float*)gw, (const float*)ow,
                         (const float*)tb2, (const float*)fb, (const float*)gb, (const float*)ob,
                         Wb, OWb, Bf, OBf);
    else
        prep_body<__hip_bfloat16>((const __hip_bfloat16*)tw, (const __hip_bfloat16*)fw,
                                  (const __hip_bfloat16*)gw, (const __hip_bfloat16*)ow,
                                  (const __hip_bfloat16*)tb2, (const __hip_bfloat16*)fb,
                                  (const __hip_bfloat16*)gb, (const __hip_bfloat16*)ob,
                                  Wb, OWb, Bf, OBf);
}

// ---------------------------------------------------------------------------
// Kernel 2: xt[b][p][c] = bf16(x[b][c][p]) (proven round 6).
// ---------------------------------------------------------------------------
template <typename T>
__device__ __forceinline__ void xtrans_body(const T* __restrict__ x, unsigned short* __restrict__ xt) {
    int b = blockIdx.z;
    const T* in = x + (size_t)b * CC * NN;
    unsigned short* out = xt + (size_t)b * NN * CC;
    int p0 = blockIdx.x * 64, c0 = blockIdx.y * 64;
    __shared__ unsigned short t[64][68];
    int flat = threadIdx.x;
#pragma unroll
    for (int tt = 0; tt < 16; ++tt) {
        int id = flat + tt * 256;
        int rr = id >> 6, cc = id & 63;
        t[cc][rr] = f2bf(to_f(in[(size_t)(c0 + rr) * NN + p0 + cc]));
    }
    __syncthreads();
#pragma unroll
    for (int tt = 0; tt < 16; ++tt) {
        int id = flat + tt * 256;
        int pp = id >> 6, jj = id & 63;
        out[(size_t)(p0 + pp) * CC + c0 + jj] = t[pp][jj];
    }
}

__launch_bounds__(256)
__global__ void xtrans_kernel(const void* x, const int* __restrict__ flag,
                              unsigned short* __restrict__ xt) {
    if (*flag) xtrans_body<float>((const float*)x, xt);
    else       xtrans_body<__hip_bfloat16>((const __hip_bfloat16*)x, xt);
}

// ---------------------------------------------------------------------------
// Kernel 3: three 1x1 convs via MFMA.
//   cv=0 (theta): natural (CH,N) store -> T1b (== (N,CH) view).
//   cv=1 (phi):   T2t[p*128+o] written directly via 16x16 in-wave shfl
//                 transpose (audited: lane l' pulls D[o0+(l'&3)*4+k][p0+l'>>2]).
//   cv=2 (g):     natural store -> T3b. X3t CANNOT be fused (round-11 bug);
//                 standalone transpose reinstated below.
// ---------------------------------------------------------------------------
__launch_bounds__(256)
__global__ void conv3_mfma_kernel(const unsigned short* __restrict__ xt,
                                  const unsigned short* __restrict__ Wb,
                                  const float* __restrict__ Bf,
                                  unsigned short* __restrict__ T1b,
                                  unsigned short* __restrict__ T2t,
                                  unsigned short* __restrict__ T3b) {
    int b = blockIdx.y;
    int p0 = blockIdx.x * 16;
    int flat = threadIdx.x;
    int w = flat >> 6, lane = flat & 63, m = lane & 15, quad = lane >> 4;
    const unsigned short* xrow = xt + ((size_t)b * NN + p0 + m) * CC;
    bf16x8 xf[8];
#pragma unroll
    for (int kc = 0; kc < 8; ++kc)
        xf[kc] = ldb8(&xrow[kc * 32 + quad * 8]);
    unsigned short* t1  = T1b + (size_t)b * CHH * NN;
    unsigned short* t2t = T2t + (size_t)b * CHH * NN;   // [p][o], row stride 128
    unsigned short* t3  = T3b + (size_t)b * CHH * NN;   // natural (CH,N)
#pragma unroll
    for (int q = 0; q < 6; ++q) {
        int t = w * 6 + q;
        int cv = t >> 3, ot = t & 7;
        int o0 = ot * 16;
        const unsigned short* wrow = Wb + ((size_t)cv * CHH + o0 + m) * CC;
        f32x4 acc = {0.f, 0.f, 0.f, 0.f};
#pragma unroll
        for (int kc = 0; kc < 8; ++kc) {
            bf16x8 wf = ldb8(&wrow[kc * 32 + quad * 8]);
            acc = __builtin_amdgcn_mfma_f32_16x16x32_bf16(wf, xf[kc], acc, 0, 0, 0);
        }
        unsigned short hv[4];
#pragma unroll
        for (int r = 0; r < 4; ++r)
            hv[r] = f2bf(acc[r] + Bf[cv * CHH + o0 + quad * 4 + r]);
        if (cv == 1) {
            unsigned int lo = (unsigned int)hv[0] | ((unsigned int)hv[1] << 16);
            unsigned int hi = (unsigned int)hv[2] | ((unsigned int)hv[3] << 16);
            int src = (lane & 3) * 16 + (lane >> 2);
            unsigned int tlo = (unsigned int)__shfl((int)lo, src, 64);
            unsigned int thi = (unsigned int)__shfl((int)hi, src, 64);
            unsigned int* dst = (unsigned int*)&t2t[(size_t)(p0 + (lane >> 2)) * CHH +
                                                    o0 + (lane & 3) * 4];
            dst[0] = tlo;
            dst[1] = thi;
        } else {
            unsigned short* outp = (cv == 0) ? t1 : t3;
#pragma unroll
            for (int r = 0; r < 4; ++r)
                outp[(size_t)(o0 + quad * 4 + r) * NN + p0 + m] = hv[r];
        }
    }
}

// ---------------------------------------------------------------------------
// Kernel 4: generic bf16 tiled transpose (proven) — X3t only.
// ---------------------------------------------------------------------------
__launch_bounds__(256)
__global__ void transpose_kernel(const unsigned short* __restrict__ in,
                                 unsigned short* __restrict__ out, int R, int C) {
    int bz = blockIdx.z;
    in  += (size_t)bz * R * C;
    out += (size_t)bz * R * C;
    int c0 = blockIdx.x * 64, r0 = blockIdx.y * 64;
    __shared__ unsigned short t[64][68];
    int flat = threadIdx.x;
#pragma unroll
    for (int tt = 0; tt < 16; ++tt) {
        int id = flat + tt * 256;
        int r = id >> 6, c = id & 63;
        t[c][r] = in[(size_t)(r0 + r) * C + c0 + c];
    }
    __syncthreads();
#pragma unroll
    for (int tt = 0; tt < 16; ++tt) {
        int id = flat + tt * 256;
        int c = id >> 6, r = id & 63;
        out[(size_t)(c0 + c) * R + r0 + r] = t[c][r];
    }
}

// ---------------------------------------------------------------------------
// Kernel 5 (pass A): colsum exp(S-K). ROUND 12: double-buffered theta tile +
// single barrier per tile (stage t+1 issued BEFORE compute of t, so the
// vmcnt(0) drain inside __syncthreads lands after a full compute phase —
// T3-minimum pipeline). Grid 1024, LDS 32 KB.
// ---------------------------------------------------------------------------
__launch_bounds__(256)
__global__ void stats_mfma_kernel(const unsigned short* __restrict__ T1b,
                                  const unsigned short* __restrict__ T2t,
                                  float* __restrict__ Lpart) {
    int blk = blockIdx.x;
    int b = (blk & 7) >> 1;
    int rest = (blk >> 3) * 2 + (blk & 1);   // 0..255 = strip*8 + iq
    int strip = rest >> 3, iq = rest & 7;
    int ibase = iq * 512;
    int flat = threadIdx.x;
    int w = flat >> 6, lane = flat & 63, m = lane & 15, quad = lane >> 4;
    const unsigned short* A  = T1b + (size_t)b * CHH * NN;
    const unsigned short* Bt = T2t + (size_t)b * CHH * NN;
    __shared__ unsigned short th[2][64 * 128];   // double-buffered theta tile

    int u0w = strip * 128 + w * 32;           // this wave's 32-u window
    bf16x8 bfr[2][4];
#pragma unroll
    for (int g = 0; g < 2; ++g)
#pragma unroll
        for (int kc = 0; kc < 4; ++kc)
            bfr[g][kc] = ldb8(&Bt[(size_t)(u0w + g * 16 + m) * CHH + kc * 32 + quad * 8]);

#define STAGE_TH(dst, ii)                                                          \
    _Pragma("unroll")                                                              \
    for (int i_ = 0; i_ < 4; ++i_) {                                               \
        int sl = i_ * 256 + flat;                                                  \
        int r_ = sl >> 4, ch_ = sl & 15;                                           \
        int c_ = ch_ ^ (r_ & 7);                                                   \
        gload_lds16(&A[(size_t)((ii) + r_) * CHH + c_ * 8], &th[dst][sl * 8]);     \
    }

    float csum[2] = {0.f, 0.f};
    STAGE_TH(0, ibase);                      // prologue: tile 0
    __syncthreads();                         // tile 0 ready (vmcnt drained)
    int cur = 0;
    for (int t = 0; t < 8; ++t) {            // 8 i-tiles of 64 in this chunk
        if (t < 7) { STAGE_TH(cur ^ 1, ibase + (t + 1) * 64); }
        const unsigned short* thc = th[cur];
#pragma unroll
        for (int s = 0; s < 4; ++s) {
            int irow = s * 16 + m;
            bf16x8 af[4];
#pragma unroll
            for (int kc = 0; kc < 4; ++kc) {
                int ch = (kc * 4 + quad) ^ (irow & 7);
                af[kc] = *(const bf16x8*)&thc[irow * 128 + ch * 8];
            }
#pragma unroll
            for (int g = 0; g < 2; ++g) {
                f32x4 acc = {0.f, 0.f, 0.f, 0.f};
#pragma unroll
                for (int kc = 0; kc < 4; ++kc)
                    acc = __builtin_amdgcn_mfma_f32_16x16x32_bf16(af[kc], bfr[g][kc], acc, 0, 0, 0);
#pragma unroll
                for (int r = 0; r < 4; ++r)
                    csum[g] += __expf(acc[r] - KSHIFT);
            }
        }
        if (t < 7) {
            __syncthreads();                 // publishes tile t+1, protects buf t
            cur ^= 1;
        }
    }
#undef STAGE_TH
#pragma unroll
    for (int g = 0; g < 2; ++g) {
        csum[g] += __shfl_xor(csum[g], 16, 64);
        csum[g] += __shfl_xor(csum[g], 32, 64);
        if (lane < 16)
            Lpart[((size_t)iq * BB + b) * NN + u0w + g * 16 + m] = csum[g];
    }
}

// ---------------------------------------------------------------------------
// Kernel 6 (pass B): Y = P @ X3. ROUND 12: double-buffered bt/x3 tiles +
// single barrier per u-tile (T3-minimum pipeline; staging latency hidden
// under the S/PV compute phase). LDS 79.9 KB -> still 2 blocks/CU (grid 512
// is 2/CU regardless). Machinery otherwise proven rounds 8-10.
// ---------------------------------------------------------------------------
__launch_bounds__(256)
__global__ void attn_mfma_kernel(const unsigned short* __restrict__ T1b,
                                 const unsigned short* __restrict__ T2t,
                                 const unsigned short* __restrict__ X3t,
                                 const float* __restrict__ Lpart,
                                 unsigned short* __restrict__ Yp0,
                                 unsigned short* __restrict__ Yp1,
                                 unsigned short* __restrict__ Yp2,
                                 unsigned short* __restrict__ Yp3) {
    int blk = blockIdx.x;
    int b = (blk & 7) >> 1;
    int rest = (blk >> 3) * 2 + (blk & 1);   // 0..127 = it*4 + uc
    int it = rest >> 2, uc = rest & 3;
    int i0 = it * 128;
    unsigned short* Yp = uc == 0 ? Yp0 : (uc == 1 ? Yp1 : (uc == 2 ? Yp2 : Yp3));
    int flat = threadIdx.x;                   // 0..255
    int w = flat >> 6, lane = flat & 63, m = lane & 15, quad = lane >> 4;
    const unsigned short* A  = T1b + (size_t)b * CHH * NN;
    const unsigned short* Bt = T2t + (size_t)b * CHH * NN;
    const unsigned short* X3 = X3t + (size_t)b * CHH * NN;

    __shared__ unsigned short bt[2][64 * 128];  // phi^T tile, swizzled, dbuf
    __shared__ unsigned short x3[2][128 * 64];  // X3 tile, swizzled, dbuf
    __shared__ unsigned short pT[4][2][16][40]; // wave-private P half-tiles
    __shared__ float llh[1024];               // this chunk's LL values

    int ubeg = uc * 1024;
#pragma unroll
    for (int k = 0; k < 4; ++k) {             // LL prologue (replaces lmerge)
        int idx = k * 256 + flat;
        int u = ubeg + idx;
        float s = 0.f;
#pragma unroll
        for (int c = 0; c < 8; ++c)
            s += Lpart[((size_t)c * BB + b) * NN + u];
        llh[idx] = logf(s) + KSHIFT;
    }

    int iw = i0 + w * 32;
    bf16x8 ath[2][4];
#pragma unroll
    for (int g = 0; g < 2; ++g)
#pragma unroll
        for (int kc = 0; kc < 4; ++kc)
            ath[g][kc] = ldb8(&A[(size_t)(iw + g * 16 + m) * CHH + kc * 32 + quad * 8]);
    f32x4 yacc[2][8];
#pragma unroll
    for (int g = 0; g < 2; ++g)
#pragma unroll
        for (int js = 0; js < 8; ++js) yacc[g][js] = (f32x4){0.f, 0.f, 0.f, 0.f};

#define STAGE_UT(dst, uu)                                                          \
    _Pragma("unroll")                                                              \
    for (int i_ = 0; i_ < 4; ++i_) {          /* stage Bt tile (16 KB) */          \
        int sl = i_ * 256 + flat;                                                  \
        int u_ = sl >> 4, ch_ = sl & 15;                                           \
        int c_ = ch_ ^ (u_ & 7);                                                   \
        gload_lds16(&Bt[(size_t)((uu) + u_) * CHH + c_ * 8], &bt[dst][sl * 8]);    \
    }                                                                              \
    _Pragma("unroll")                                                              \
    for (int i_ = 0; i_ < 4; ++i_) {          /* stage X3 tile (16 KB) */          \
        int sl = i_ * 256 + flat;                                                  \
        int j_ = sl >> 3, ch_ = sl & 7;                                            \
        int c_ = ch_ ^ (j_ & 7);                                                   \
        gload_lds16(&X3[(size_t)j_ * NN + (uu) + c_ * 8], &x3[dst][sl * 8]);       \
    }

    STAGE_UT(0, ubeg);                        // prologue: tile 0
    __syncthreads();                          // tile 0 + llh visible
    int cur = 0;
    for (int t = 0; t < 16; ++t) {
        int u0 = ubeg + t * 64;
        if (t < 15) { STAGE_UT(cur ^ 1, u0 + 64); }  // issue next tile EARLY
        const unsigned short* btc = bt[cur];
        const unsigned short* x3c = x3[cur];
#pragma unroll
        for (int h = 0; h < 2; ++h) {         // two 32-u halves
            // ---- S phase: S(32i x 32u), exp, P -> wave-private LDS ----
#pragma unroll
            for (int su = 0; su < 2; ++su) {
                int u = h * 32 + su * 16 + m;
                f32x4 a0 = {0.f, 0.f, 0.f, 0.f}, a1 = {0.f, 0.f, 0.f, 0.f};
#pragma unroll
                for (int kc = 0; kc < 4; ++kc) {
                    int ch = (kc * 4 + quad) ^ (u & 7);
                    bf16x8 bf = *(const bf16x8*)&btc[u * 128 + ch * 8];
                    a0 = __builtin_amdgcn_mfma_f32_16x16x32_bf16(ath[0][kc], bf, a0, 0, 0, 0);
                    a1 = __builtin_amdgcn_mfma_f32_16x16x32_bf16(ath[1][kc], bf, a1, 0, 0, 0);
                }
                float ll = llh[u0 - ubeg + u];
#pragma unroll
                for (int r = 0; r < 4; ++r) {
                    pT[w][0][quad * 4 + r][su * 16 + m] = f2bf(__expf(a0[r] - ll));
                    pT[w][1][quad * 4 + r][su * 16 + m] = f2bf(__expf(a1[r] - ll));
                }
            }
            // ---- PV phase: Y(32i x 128j) += P_half @ X3_half ----
            bf16x8 pa0 = *(const bf16x8*)&pT[w][0][m][quad * 8];
            bf16x8 pa1 = *(const bf16x8*)&pT[w][1][m][quad * 8];
#pragma unroll
            for (int js = 0; js < 8; ++js) {
                int j = js * 16 + m;
                int ch = (h * 4 + quad) ^ (j & 7);
                bf16x8 xb = *(const bf16x8*)&x3c[j * 64 + ch * 8];
                yacc[0][js] = __builtin_amdgcn_mfma_f32_16x16x32_bf16(pa0, xb, yacc[0][js], 0, 0, 0);
                yacc[1][js] = __builtin_amdgcn_mfma_f32_16x16x32_bf16(pa1, xb, yacc[1][js], 0, 0, 0);
            }
        }
        if (t < 15) {
            __syncthreads();                  // publishes tile t+1, protects buf t
            cur ^= 1;
        }
    }
#undef STAGE_UT
#pragma unroll
    for (int g = 0; g < 2; ++g)
#pragma unroll
        for (int js = 0; js < 8; ++js)
#pragma unroll
            for (int r = 0; r < 4; ++r)
                Yp[((size_t)b * NN + iw + g * 16 + quad * 4 + r) * CHH + js * 16 + m] =
                    f2bf(yacc[g][js][r]);
}

// ---------------------------------------------------------------------------
// Kernel 7: out = x + out_w @ (Yp0+Yp1+Yp2+Yp3)^T + out_b via MFMA
// (proven round 10; partials merged in the fp32 accumulator).
// ---------------------------------------------------------------------------
template <typename T>
__device__ __forceinline__ void outconv_body(const T* __restrict__ x,
                                             const unsigned short* __restrict__ Yp0,
                                             const unsigned short* __restrict__ Yp1,
                                             const unsigned short* __restrict__ Yp2,
                                             const unsigned short* __restrict__ Yp3,
                                             const unsigned short* __restrict__ OWb,
                                             const float* __restrict__ OBf,
                                             T* __restrict__ out) {
    int b = blockIdx.y;
    int p0 = blockIdx.x * 16;
    int flat = threadIdx.x;
    int w = flat >> 6, lane = flat & 63, m = lane & 15, quad = lane >> 4;
    size_t yoff = ((size_t)b * NN + p0 + m) * CHH;
    const unsigned short* yrows[4] = {Yp0 + yoff, Yp1 + yoff, Yp2 + yoff, Yp3 + yoff};
    bf16x8 yf[4][4];
#pragma unroll
    for (int pz = 0; pz < 4; ++pz)
#pragma unroll
        for (int kc = 0; kc < 4; ++kc)
            yf[pz][kc] = ldb8(&yrows[pz][kc * 32 + quad * 8]);
#pragma unroll
    for (int q = 0; q < 4; ++q) {
        int o0 = (w * 4 + q) * 16;
        const unsigned short* wrow = OWb + (size_t)(o0 + m) * CHH;
        f32x4 acc = {0.f, 0.f, 0.f, 0.f};
#pragma unroll
        for (int kc = 0; kc < 4; ++kc) {
            bf16x8 aw = ldb8(&wrow[kc * 32 + quad * 8]);
#pragma unroll
            for (int pz = 0; pz < 4; ++pz)
                acc = __builtin_amdgcn_mfma_f32_16x16x32_bf16(aw, yf[pz][kc], acc, 0, 0, 0);
        }
#pragma unroll
        for (int r = 0; r < 4; ++r) {
            int co = o0 + quad * 4 + r;
            size_t oi = ((size_t)b * CC + co) * NN + p0 + m;
            st_f(&out[oi], acc[r] + OBf[co] + to_f(x[oi]));
        }
    }
}

__launch_bounds__(256)
__global__ void outconv_mfma_kernel(const void* x,
                                    const unsigned short* __restrict__ Yp0,
                                    const unsigned short* __restrict__ Yp1,
                                    const unsigned short* __restrict__ Yp2,
                                    const unsigned short* __restrict__ Yp3,
                                    const unsigned short* __restrict__ OWb,
                                    const float* __restrict__ OBf,
                                    const int* __restrict__ flag, void* out) {
    if (*flag)
        outconv_body<float>((const float*)x, Yp0, Yp1, Yp2, Yp3, OWb, OBf, (float*)out);
    else
        outconv_body<__hip_bfloat16>((const __hip_bfloat16*)x, Yp0, Yp1, Yp2, Yp3, OWb, OBf,
                                     (__hip_bfloat16*)out);
}

extern "C" void kernel_launch(void* const* d_in, const int* in_sizes, int n_in,
                              void* d_out, int out_size, void* d_ws, size_t ws_size,
                              hipStream_t stream) {
    const void* x  = d_in[0];
    const void* tw = d_in[1];
    const void* tb = d_in[2];
    const void* fw = d_in[3];
    const void* fb = d_in[4];
    const void* gw = d_in[5];
    const void* gb = d_in[6];
    const void* ow = d_in[7];
    const void* ob = d_in[8];

    // Workspace (~30 MB): conv3 writes T1b natural, T2t fused-transposed,
    // T3b natural; transpose T3b -> X3t. Aliases: Yp0/Yp1 <- xt (dead after
    // conv3), Yp2 <- T3b (dead after the X3t transpose), Yp3 fresh.
    const size_t TE = (size_t)BB * CHH * NN;        // 2,097,152
    unsigned short* T1b = (unsigned short*)d_ws;
    unsigned short* T2t = T1b + TE;                 // phi transposed [p][o]
    unsigned short* X3t = T2t + TE;                 // g-view transposed [j][u]
    unsigned short* T3b = X3t + TE;                 // g natural (CH,N)
    unsigned short* xt  = T3b + TE;                 // 2*TE shorts (dead after conv3)
    unsigned short* Yp0 = xt;                       // alias
    unsigned short* Yp1 = xt + TE;                  // alias
    unsigned short* Yp2 = T3b;                      // alias (dead after transpose)
    unsigned short* Yp3 = xt + 2 * TE;              // fresh
    unsigned short* Wb  = Yp3 + TE;                 // 98304 shorts
    unsigned short* OWb = Wb + 98304;               // 32768 shorts
    float* Bf    = (float*)(OWb + 32768);           // 384
    float* OBf   = Bf + 384;                        // 256
    float* Lpart = OBf + 256;                       // 8 * BB * NN = 131072
    int*   Flag  = (int*)(Lpart + 131072);

    detect_kernel<<<1, 64, 0, stream>>>(tb, Flag);
    prep_kernel<<<dim3(515), 256, 0, stream>>>(tw, fw, gw, ow, tb, fb, gb, ob,
                                               Flag, Wb, OWb, Bf, OBf);
    xtrans_kernel<<<dim3(NN / 64, CC / 64, BB), 256, 0, stream>>>(x, Flag, xt);
    conv3_mfma_kernel<<<dim3(NN / 16, BB), 256, 0, stream>>>(xt, Wb, Bf, T1b, T2t, T3b);
    transpose_kernel<<<dim3(CHH / 64, NN / 64, BB), 256, 0, stream>>>(T3b, X3t, NN, CHH);
    stats_mfma_kernel<<<dim3(1024), 256, 0, stream>>>(T1b, T2t, Lpart);
    attn_mfma_kernel<<<dim3(512), 256, 0, stream>>>(T1b, T2t, X3t, Lpart, Yp0, Yp1, Yp2, Yp3);
    outconv_mfma_kernel<<<dim3(NN / 16, BB), 256, 0, stream>>>(x, Yp0, Yp1, Yp2, Yp3,
                                                               OWb, OBf, Flag, d_out);
}

// Round 2
// 212.540 us; speedup vs baseline: 1.0216x; 1.0216x over previous
//
#include <hip/hip_runtime.h>
#include <hip/hip_bf16.h>

#define BB 4
#define CC 256
#define CHH 128
#define NN 4096
#define KSHIFT 12.0f

typedef __attribute__((ext_vector_type(8))) short bf16x8;
typedef __attribute__((ext_vector_type(4))) float f32x4;

__device__ __forceinline__ float to_f(float v) { return v; }
__device__ __forceinline__ float to_f(__hip_bfloat16 v) { return __bfloat162float(v); }
__device__ __forceinline__ void st_f(float* p, float v) { *p = v; }
__device__ __forceinline__ void st_f(__hip_bfloat16* p, float v) { *p = __float2bfloat16(v); }
__device__ __forceinline__ unsigned short f2bf(float f) {
    __hip_bfloat16 h = __float2bfloat16(f);
    unsigned short u;
    __builtin_memcpy(&u, &h, 2);
    return u;
}
__device__ __forceinline__ bf16x8 ldb8(const unsigned short* p) { return *(const bf16x8*)p; }

// async global->LDS, 16 B per lane. LDS dest = wave-uniform base + lane*16.
__device__ __forceinline__ void gload_lds16(const unsigned short* g, unsigned short* l) {
    __builtin_amdgcn_global_load_lds(
        (const __attribute__((address_space(1))) unsigned int*)g,
        (__attribute__((address_space(3))) unsigned int*)l, 16, 0, 0);
}

// ---------------------------------------------------------------------------
// Kernel 0: wire-dtype detection (proven rounds 3-10 — keep).
// ---------------------------------------------------------------------------
__global__ void detect_kernel(const void* __restrict__ tb, int* __restrict__ flag) {
    if (threadIdx.x == 0) {
        const __hip_bfloat16* p = (const __hip_bfloat16*)tb;
        int big = 0, zeros = 0;
        for (int i = 0; i < 128; ++i) {
            float v = __bfloat162float(p[i]);
            if (!(fabsf(v) <= 0.5f)) big = 1;
            if ((i & 1) == 0 && v == 0.0f) zeros++;
        }
        *flag = (big || zeros >= 32) ? 1 : 0;
    }
}

// ---------------------------------------------------------------------------
// Kernel 1: convert all weights/biases once (proven round 6).
// ---------------------------------------------------------------------------
template <typename T>
__device__ __forceinline__ void prep_body(const T* tw, const T* fw, const T* gw, const T* ow,
                                          const T* tb2, const T* fb, const T* gb, const T* ob,
                                          unsigned short* Wb, unsigned short* OWb,
                                          float* Bf, float* OBf) {
    int idx = blockIdx.x * 256 + threadIdx.x;
    if (idx < 98304) {
        int cv = idx >> 15, rem = idx & 32767;
        const T* src = cv == 0 ? tw : (cv == 1 ? fw : gw);
        Wb[idx] = f2bf(to_f(src[rem]));
    } else if (idx < 131072) {
        OWb[idx - 98304] = f2bf(to_f(ow[idx - 98304]));
    } else if (idx < 131456) {
        int r = idx - 131072;
        int cv = r >> 7, j = r & 127;
        const T* src = cv == 0 ? tb2 : (cv == 1 ? fb : gb);
        Bf[r] = to_f(src[j]);
    } else if (idx < 131712) {
        OBf[idx - 131456] = to_f(ob[idx - 131456]);
    }
}

__global__ void prep_kernel(const void* tw, const void* fw, const void* gw, const void* ow,
                            const void* tb2, const void* fb, const void* gb, const void* ob,
                            const int* __restrict__ flag,
                            unsigned short* Wb, unsigned short* OWb, float* Bf, float* OBf) {
    if (*flag)
        prep_body<float>((const float*)tw, (const float*)fw, (const float*)gw, (const float*)ow,
                         (const float*)tb2, (const float*)fb, (const float*)gb, (const float*)ob,
                         Wb, OWb, Bf, OBf);
    else
        prep_body<__hip_bfloat16>((const __hip_bfloat16*)tw, (const __hip_bfloat16*)fw,
                                  (const __hip_bfloat16*)gw, (const __hip_bfloat16*)ow,
                                  (const __hip_bfloat16*)tb2, (const __hip_bfloat16*)fb,
                                  (const __hip_bfloat16*)gb, (const __hip_bfloat16*)ob,
                                  Wb, OWb, Bf, OBf);
}

// ---------------------------------------------------------------------------
// Kernel 2: xt[b][p][c] = bf16(x[b][c][p]) (proven round 6).
// ---------------------------------------------------------------------------
template <typename T>
__device__ __forceinline__ void xtrans_body(const T* __restrict__ x, unsigned short* __restrict__ xt) {
    int b = blockIdx.z;
    const T* in = x + (size_t)b * CC * NN;
    unsigned short* out = xt + (size_t)b * NN * CC;
    int p0 = blockIdx.x * 64, c0 = blockIdx.y * 64;
    __shared__ unsigned short t[64][68];
    int flat = threadIdx.x;
#pragma unroll
    for (int tt = 0; tt < 16; ++tt) {
        int id = flat + tt * 256;
        int rr = id >> 6, cc = id & 63;
        t[cc][rr] = f2bf(to_f(in[(size_t)(c0 + rr) * NN + p0 + cc]));
    }
    __syncthreads();
#pragma unroll
    for (int tt = 0; tt < 16; ++tt) {
        int id = flat + tt * 256;
        int pp = id >> 6, jj = id & 63;
        out[(size_t)(p0 + pp) * CC + c0 + jj] = t[pp][jj];
    }
}

__launch_bounds__(256)
__global__ void xtrans_kernel(const void* x, const int* __restrict__ flag,
                              unsigned short* __restrict__ xt) {
    if (*flag) xtrans_body<float>((const float*)x, xt);
    else       xtrans_body<__hip_bfloat16>((const __hip_bfloat16*)x, xt);
}

// ---------------------------------------------------------------------------
// Kernel 3: three 1x1 convs via MFMA.
//   cv=0 (theta): natural (CH,N) store -> T1b (== (N,CH) view).
//   cv=1 (phi):   T2t[p*128+o] written directly via 16x16 in-wave shfl
//                 transpose (audited: lane l' pulls D[o0+(l'&3)*4+k][p0+l'>>2]).
//   cv=2 (g):     natural store -> T3b. X3t CANNOT be fused (round-11 bug);
//                 standalone transpose reinstated below.
// ---------------------------------------------------------------------------
__launch_bounds__(256)
__global__ void conv3_mfma_kernel(const unsigned short* __restrict__ xt,
                                  const unsigned short* __restrict__ Wb,
                                  const float* __restrict__ Bf,
                                  unsigned short* __restrict__ T1b,
                                  unsigned short* __restrict__ T2t,
                                  unsigned short* __restrict__ T3b) {
    int b = blockIdx.y;
    int p0 = blockIdx.x * 16;
    int flat = threadIdx.x;
    int w = flat >> 6, lane = flat & 63, m = lane & 15, quad = lane >> 4;
    const unsigned short* xrow = xt + ((size_t)b * NN + p0 + m) * CC;
    bf16x8 xf[8];
#pragma unroll
    for (int kc = 0; kc < 8; ++kc)
        xf[kc] = ldb8(&xrow[kc * 32 + quad * 8]);
    unsigned short* t1  = T1b + (size_t)b * CHH * NN;
    unsigned short* t2t = T2t + (size_t)b * CHH * NN;   // [p][o], row stride 128
    unsigned short* t3  = T3b + (size_t)b * CHH * NN;   // natural (CH,N)
#pragma unroll
    for (int q = 0; q < 6; ++q) {
        int t = w * 6 + q;
        int cv = t >> 3, ot = t & 7;
        int o0 = ot * 16;
        const unsigned short* wrow = Wb + ((size_t)cv * CHH + o0 + m) * CC;
        f32x4 acc = {0.f, 0.f, 0.f, 0.f};
#pragma unroll
        for (int kc = 0; kc < 8; ++kc) {
            bf16x8 wf = ldb8(&wrow[kc * 32 + quad * 8]);
            acc = __builtin_amdgcn_mfma_f32_16x16x32_bf16(wf, xf[kc], acc, 0, 0, 0);
        }
        unsigned short hv[4];
#pragma unroll
        for (int r = 0; r < 4; ++r)
            hv[r] = f2bf(acc[r] + Bf[cv * CHH + o0 + quad * 4 + r]);
        if (cv == 1) {
            unsigned int lo = (unsigned int)hv[0] | ((unsigned int)hv[1] << 16);
            unsigned int hi = (unsigned int)hv[2] | ((unsigned int)hv[3] << 16);
            int src = (lane & 3) * 16 + (lane >> 2);
            unsigned int tlo = (unsigned int)__shfl((int)lo, src, 64);
            unsigned int thi = (unsigned int)__shfl((int)hi, src, 64);
            unsigned int* dst = (unsigned int*)&t2t[(size_t)(p0 + (lane >> 2)) * CHH +
                                                    o0 + (lane & 3) * 4];
            dst[0] = tlo;
            dst[1] = thi;
        } else {
            unsigned short* outp = (cv == 0) ? t1 : t3;
#pragma unroll
            for (int r = 0; r < 4; ++r)
                outp[(size_t)(o0 + quad * 4 + r) * NN + p0 + m] = hv[r];
        }
    }
}

// ---------------------------------------------------------------------------
// Kernel 4: generic bf16 tiled transpose (proven) — X3t only.
// ---------------------------------------------------------------------------
__launch_bounds__(256)
__global__ void transpose_kernel(const unsigned short* __restrict__ in,
                                 unsigned short* __restrict__ out, int R, int C) {
    int bz = blockIdx.z;
    in  += (size_t)bz * R * C;
    out += (size_t)bz * R * C;
    int c0 = blockIdx.x * 64, r0 = blockIdx.y * 64;
    __shared__ unsigned short t[64][68];
    int flat = threadIdx.x;
#pragma unroll
    for (int tt = 0; tt < 16; ++tt) {
        int id = flat + tt * 256;
        int r = id >> 6, c = id & 63;
        t[c][r] = in[(size_t)(r0 + r) * C + c0 + c];
    }
    __syncthreads();
#pragma unroll
    for (int tt = 0; tt < 16; ++tt) {
        int id = flat + tt * 256;
        int c = id >> 6, r = id & 63;
        out[(size_t)(c0 + c) * R + r0 + r] = t[c][r];
    }
}

// ---------------------------------------------------------------------------
// Kernel 5 (pass A): colsum exp(S-K). Round 12 double-buffered theta tile +
// single barrier per tile. Grid 1024 (4 blocks/CU x 4 waves = 4 waves/SIMD
// already), LDS 32 KB. Unchanged this round.
// ---------------------------------------------------------------------------
__launch_bounds__(256)
__global__ void stats_mfma_kernel(const unsigned short* __restrict__ T1b,
                                  const unsigned short* __restrict__ T2t,
                                  float* __restrict__ Lpart) {
    int blk = blockIdx.x;
    int b = (blk & 7) >> 1;
    int rest = (blk >> 3) * 2 + (blk & 1);   // 0..255 = strip*8 + iq
    int strip = rest >> 3, iq = rest & 7;
    int ibase = iq * 512;
    int flat = threadIdx.x;
    int w = flat >> 6, lane = flat & 63, m = lane & 15, quad = lane >> 4;
    const unsigned short* A  = T1b + (size_t)b * CHH * NN;
    const unsigned short* Bt = T2t + (size_t)b * CHH * NN;
    __shared__ unsigned short th[2][64 * 128];   // double-buffered theta tile

    int u0w = strip * 128 + w * 32;           // this wave's 32-u window
    bf16x8 bfr[2][4];
#pragma unroll
    for (int g = 0; g < 2; ++g)
#pragma unroll
        for (int kc = 0; kc < 4; ++kc)
            bfr[g][kc] = ldb8(&Bt[(size_t)(u0w + g * 16 + m) * CHH + kc * 32 + quad * 8]);

#define STAGE_TH(dst, ii)                                                          \
    _Pragma("unroll")                                                              \
    for (int i_ = 0; i_ < 4; ++i_) {                                               \
        int sl = i_ * 256 + flat;                                                  \
        int r_ = sl >> 4, ch_ = sl & 15;                                           \
        int c_ = ch_ ^ (r_ & 7);                                                   \
        gload_lds16(&A[(size_t)((ii) + r_) * CHH + c_ * 8], &th[dst][sl * 8]);     \
    }

    float csum[2] = {0.f, 0.f};
    STAGE_TH(0, ibase);                      // prologue: tile 0
    __syncthreads();                         // tile 0 ready (vmcnt drained)
    int cur = 0;
    for (int t = 0; t < 8; ++t) {            // 8 i-tiles of 64 in this chunk
        if (t < 7) { STAGE_TH(cur ^ 1, ibase + (t + 1) * 64); }
        const unsigned short* thc = th[cur];
#pragma unroll
        for (int s = 0; s < 4; ++s) {
            int irow = s * 16 + m;
            bf16x8 af[4];
#pragma unroll
            for (int kc = 0; kc < 4; ++kc) {
                int ch = (kc * 4 + quad) ^ (irow & 7);
                af[kc] = *(const bf16x8*)&thc[irow * 128 + ch * 8];
            }
#pragma unroll
            for (int g = 0; g < 2; ++g) {
                f32x4 acc = {0.f, 0.f, 0.f, 0.f};
#pragma unroll
                for (int kc = 0; kc < 4; ++kc)
                    acc = __builtin_amdgcn_mfma_f32_16x16x32_bf16(af[kc], bfr[g][kc], acc, 0, 0, 0);
#pragma unroll
                for (int r = 0; r < 4; ++r)
                    csum[g] += __expf(acc[r] - KSHIFT);
            }
        }
        if (t < 7) {
            __syncthreads();                 // publishes tile t+1, protects buf t
            cur ^= 1;
        }
    }
#undef STAGE_TH
#pragma unroll
    for (int g = 0; g < 2; ++g) {
        csum[g] += __shfl_xor(csum[g], 16, 64);
        csum[g] += __shfl_xor(csum[g], 32, 64);
        if (lane < 16)
            Lpart[((size_t)iq * BB + b) * NN + u0w + g * 16 + m] = csum[g];
    }
}

// ---------------------------------------------------------------------------
// Kernel 6 (pass B): Y = P @ X3. ROUND 13: 512-thread blocks — 8 waves x
// 16 i-rows (was 4 x 32). Same 128-row i-tile, same grid 512, same LDS
// 79,872 B -> still 2 blocks/CU but now 16 waves/CU = 4 waves/SIMD (was 2).
// Per-wave state halves (ath 16 VGPR, yacc 32) so VGPR fits the
// __launch_bounds__(512,4) cap. Round-12 dbuf + single barrier kept.
// ---------------------------------------------------------------------------
__launch_bounds__(512, 4)
__global__ void attn_mfma_kernel(const unsigned short* __restrict__ T1b,
                                 const unsigned short* __restrict__ T2t,
                                 const unsigned short* __restrict__ X3t,
                                 const float* __restrict__ Lpart,
                                 unsigned short* __restrict__ Yp0,
                                 unsigned short* __restrict__ Yp1,
                                 unsigned short* __restrict__ Yp2,
                                 unsigned short* __restrict__ Yp3) {
    int blk = blockIdx.x;
    int b = (blk & 7) >> 1;
    int rest = (blk >> 3) * 2 + (blk & 1);   // 0..127 = it*4 + uc
    int it = rest >> 2, uc = rest & 3;
    int i0 = it * 128;
    unsigned short* Yp = uc == 0 ? Yp0 : (uc == 1 ? Yp1 : (uc == 2 ? Yp2 : Yp3));
    int flat = threadIdx.x;                   // 0..511
    int w = flat >> 6, lane = flat & 63, m = lane & 15, quad = lane >> 4;
    const unsigned short* A  = T1b + (size_t)b * CHH * NN;
    const unsigned short* Bt = T2t + (size_t)b * CHH * NN;
    const unsigned short* X3 = X3t + (size_t)b * CHH * NN;

    __shared__ unsigned short bt[2][64 * 128];  // phi^T tile, swizzled, dbuf
    __shared__ unsigned short x3[2][128 * 64];  // X3 tile, swizzled, dbuf
    __shared__ unsigned short pT[8][16][40];    // wave-private P tiles
    __shared__ float llh[1024];               // this chunk's LL values

    int ubeg = uc * 1024;
#pragma unroll
    for (int k = 0; k < 2; ++k) {             // LL prologue (512 threads)
        int idx = k * 512 + flat;
        int u = ubeg + idx;
        float s = 0.f;
#pragma unroll
        for (int c = 0; c < 8; ++c)
            s += Lpart[((size_t)c * BB + b) * NN + u];
        llh[idx] = logf(s) + KSHIFT;
    }

    int iw = i0 + w * 16;                     // each wave owns 16 i-rows
    bf16x8 ath[4];
#pragma unroll
    for (int kc = 0; kc < 4; ++kc)
        ath[kc] = ldb8(&A[(size_t)(iw + m) * CHH + kc * 32 + quad * 8]);
    f32x4 yacc[8];
#pragma unroll
    for (int js = 0; js < 8; ++js) yacc[js] = (f32x4){0.f, 0.f, 0.f, 0.f};

#define STAGE_UT(dst, uu)                                                          \
    _Pragma("unroll")                                                              \
    for (int i_ = 0; i_ < 2; ++i_) {          /* stage Bt tile (16 KB) */          \
        int sl = i_ * 512 + flat;                                                  \
        int u_ = sl >> 4, ch_ = sl & 15;                                           \
        int c_ = ch_ ^ (u_ & 7);                                                   \
        gload_lds16(&Bt[(size_t)((uu) + u_) * CHH + c_ * 8], &bt[dst][sl * 8]);    \
    }                                                                              \
    _Pragma("unroll")                                                              \
    for (int i_ = 0; i_ < 2; ++i_) {          /* stage X3 tile (16 KB) */          \
        int sl = i_ * 512 + flat;                                                  \
        int j_ = sl >> 3, ch_ = sl & 7;                                            \
        int c_ = ch_ ^ (j_ & 7);                                                   \
        gload_lds16(&X3[(size_t)j_ * NN + (uu) + c_ * 8], &x3[dst][sl * 8]);       \
    }

    STAGE_UT(0, ubeg);                        // prologue: tile 0
    __syncthreads();                          // tile 0 + llh visible
    int cur = 0;
    for (int t = 0; t < 16; ++t) {
        int u0 = ubeg + t * 64;
        if (t < 15) { STAGE_UT(cur ^ 1, u0 + 64); }  // issue next tile EARLY
        const unsigned short* btc = bt[cur];
        const unsigned short* x3c = x3[cur];
#pragma unroll
        for (int h = 0; h < 2; ++h) {         // two 32-u halves
            // ---- S phase: S(16i x 32u), exp, P -> wave-private LDS ----
#pragma unroll
            for (int su = 0; su < 2; ++su) {
                int u = h * 32 + su * 16 + m;
                f32x4 a0 = {0.f, 0.f, 0.f, 0.f};
#pragma unroll
                for (int kc = 0; kc < 4; ++kc) {
                    int ch = (kc * 4 + quad) ^ (u & 7);
                    bf16x8 bf = *(const bf16x8*)&btc[u * 128 + ch * 8];
                    a0 = __builtin_amdgcn_mfma_f32_16x16x32_bf16(ath[kc], bf, a0, 0, 0, 0);
                }
                float ll = llh[u0 - ubeg + u];
#pragma unroll
                for (int r = 0; r < 4; ++r)
                    pT[w][quad * 4 + r][su * 16 + m] = f2bf(__expf(a0[r] - ll));
            }
            // ---- PV phase: Y(16i x 128j) += P_half @ X3_half ----
            bf16x8 pa0 = *(const bf16x8*)&pT[w][m][quad * 8];
#pragma unroll
            for (int js = 0; js < 8; ++js) {
                int j = js * 16 + m;
                int ch = (h * 4 + quad) ^ (j & 7);
                bf16x8 xb = *(const bf16x8*)&x3c[j * 64 + ch * 8];
                yacc[js] = __builtin_amdgcn_mfma_f32_16x16x32_bf16(pa0, xb, yacc[js], 0, 0, 0);
            }
        }
        if (t < 15) {
            __syncthreads();                  // publishes tile t+1, protects buf t
            cur ^= 1;
        }
    }
#undef STAGE_UT
#pragma unroll
    for (int js = 0; js < 8; ++js)
#pragma unroll
        for (int r = 0; r < 4; ++r)
            Yp[((size_t)b * NN + iw + quad * 4 + r) * CHH + js * 16 + m] =
                f2bf(yacc[js][r]);
}

// ---------------------------------------------------------------------------
// Kernel 7: out = x + out_w @ (Yp0+Yp1+Yp2+Yp3)^T + out_b via MFMA
// (proven round 10; partials merged in the fp32 accumulator).
// ---------------------------------------------------------------------------
template <typename T>
__device__ __forceinline__ void outconv_body(const T* __restrict__ x,
                                             const unsigned short* __restrict__ Yp0,
                                             const unsigned short* __restrict__ Yp1,
                                             const unsigned short* __restrict__ Yp2,
                                             const unsigned short* __restrict__ Yp3,
                                             const unsigned short* __restrict__ OWb,
                                             const float* __restrict__ OBf,
                                             T* __restrict__ out) {
    int b = blockIdx.y;
    int p0 = blockIdx.x * 16;
    int flat = threadIdx.x;
    int w = flat >> 6, lane = flat & 63, m = lane & 15, quad = lane >> 4;
    size_t yoff = ((size_t)b * NN + p0 + m) * CHH;
    const unsigned short* yrows[4] = {Yp0 + yoff, Yp1 + yoff, Yp2 + yoff, Yp3 + yoff};
    bf16x8 yf[4][4];
#pragma unroll
    for (int pz = 0; pz < 4; ++pz)
#pragma unroll
        for (int kc = 0; kc < 4; ++kc)
            yf[pz][kc] = ldb8(&yrows[pz][kc * 32 + quad * 8]);
#pragma unroll
    for (int q = 0; q < 4; ++q) {
        int o0 = (w * 4 + q) * 16;
        const unsigned short* wrow = OWb + (size_t)(o0 + m) * CHH;
        f32x4 acc = {0.f, 0.f, 0.f, 0.f};
#pragma unroll
        for (int kc = 0; kc < 4; ++kc) {
            bf16x8 aw = ldb8(&wrow[kc * 32 + quad * 8]);
#pragma unroll
            for (int pz = 0; pz < 4; ++pz)
                acc = __builtin_amdgcn_mfma_f32_16x16x32_bf16(aw, yf[pz][kc], acc, 0, 0, 0);
        }
#pragma unroll
        for (int r = 0; r < 4; ++r) {
            int co = o0 + quad * 4 + r;
            size_t oi = ((size_t)b * CC + co) * NN + p0 + m;
            st_f(&out[oi], acc[r] + OBf[co] + to_f(x[oi]));
        }
    }
}

__launch_bounds__(256)
__global__ void outconv_mfma_kernel(const void* x,
                                    const unsigned short* __restrict__ Yp0,
                                    const unsigned short* __restrict__ Yp1,
                                    const unsigned short* __restrict__ Yp2,
                                    const unsigned short* __restrict__ Yp3,
                                    const unsigned short* __restrict__ OWb,
                                    const float* __restrict__ OBf,
                                    const int* __restrict__ flag, void* out) {
    if (*flag)
        outconv_body<float>((const float*)x, Yp0, Yp1, Yp2, Yp3, OWb, OBf, (float*)out);
    else
        outconv_body<__hip_bfloat16>((const __hip_bfloat16*)x, Yp0, Yp1, Yp2, Yp3, OWb, OBf,
                                     (__hip_bfloat16*)out);
}

extern "C" void kernel_launch(void* const* d_in, const int* in_sizes, int n_in,
                              void* d_out, int out_size, void* d_ws, size_t ws_size,
                              hipStream_t stream) {
    const void* x  = d_in[0];
    const void* tw = d_in[1];
    const void* tb = d_in[2];
    const void* fw = d_in[3];
    const void* fb = d_in[4];
    const void* gw = d_in[5];
    const void* gb = d_in[6];
    const void* ow = d_in[7];
    const void* ob = d_in[8];

    // Workspace (~30 MB): conv3 writes T1b natural, T2t fused-transposed,
    // T3b natural; transpose T3b -> X3t. Aliases: Yp0/Yp1 <- xt (dead after
    // conv3), Yp2 <- T3b (dead after the X3t transpose), Yp3 fresh.
    const size_t TE = (size_t)BB * CHH * NN;        // 2,097,152
    unsigned short* T1b = (unsigned short*)d_ws;
    unsigned short* T2t = T1b + TE;                 // phi transposed [p][o]
    unsigned short* X3t = T2t + TE;                 // g-view transposed [j][u]
    unsigned short* T3b = X3t + TE;                 // g natural (CH,N)
    unsigned short* xt  = T3b + TE;                 // 2*TE shorts (dead after conv3)
    unsigned short* Yp0 = xt;                       // alias
    unsigned short* Yp1 = xt + TE;                  // alias
    unsigned short* Yp2 = T3b;                      // alias (dead after transpose)
    unsigned short* Yp3 = xt + 2 * TE;              // fresh
    unsigned short* Wb  = Yp3 + TE;                 // 98304 shorts
    unsigned short* OWb = Wb + 98304;               // 32768 shorts
    float* Bf    = (float*)(OWb + 32768);           // 384
    float* OBf   = Bf + 384;                        // 256
    float* Lpart = OBf + 256;                       // 8 * BB * NN = 131072
    int*   Flag  = (int*)(Lpart + 131072);

    detect_kernel<<<1, 64, 0, stream>>>(tb, Flag);
    prep_kernel<<<dim3(515), 256, 0, stream>>>(tw, fw, gw, ow, tb, fb, gb, ob,
                                               Flag, Wb, OWb, Bf, OBf);
    xtrans_kernel<<<dim3(NN / 64, CC / 64, BB), 256, 0, stream>>>(x, Flag, xt);
    conv3_mfma_kernel<<<dim3(NN / 16, BB), 256, 0, stream>>>(xt, Wb, Bf, T1b, T2t, T3b);
    transpose_kernel<<<dim3(CHH / 64, NN / 64, BB), 256, 0, stream>>>(T3b, X3t, NN, CHH);
    stats_mfma_kernel<<<dim3(1024), 256, 0, stream>>>(T1b, T2t, Lpart);
    attn_mfma_kernel<<<dim3(512), 512, 0, stream>>>(T1b, T2t, X3t, Lpart, Yp0, Yp1, Yp2, Yp3);
    outconv_mfma_kernel<<<dim3(NN / 16, BB), 256, 0, stream>>>(x, Yp0, Yp1, Yp2, Yp3,
                                                               OWb, OBf, Flag, d_out);
}